// Round 7
// baseline (524.147 us; speedup 1.0000x reference)
//
#include <hip/hip_runtime.h>

typedef unsigned short u16;
typedef unsigned int   u32;

#define NN  100000
#define EE  3200000
#define ETOT 3300000   // EE + NN self-loops
#define FIN 512
#define NBUK 1024
#define NPB  98        // nodes per bucket; 1024*98 = 100352 >= NN
#define CAP  4096      // bucket capacity in buk (max real bucket ~3450)
#define TILE_A 16384   // edges per binA block
#define NBLK_A ((ETOT + TILE_A - 1) / TILE_A)   // 202
#define NBLK_G ((NN + 63) / 64)                 // 1563 gemm blocks
#define G1 600                                  // gemm blocks co-run with binA
#define G2 (NBLK_G - G1)                        // gemm blocks co-run with scatterB

typedef __attribute__((ext_vector_type(8))) short bfx8;   // 8 bf16 (4 VGPRs)
typedef __attribute__((ext_vector_type(4))) float f32x4;  // MFMA C/D

__device__ __forceinline__ float bf2f(u16 u){ return __uint_as_float(((u32)u) << 16); }
__device__ __forceinline__ float lo16f(u32 v){ return __uint_as_float(v << 16); }
__device__ __forceinline__ float hi16f(u32 v){ return __uint_as_float(v & 0xffff0000u); }
__device__ __forceinline__ u16 f2bf(float f){
  u32 u = __float_as_uint(f);
  u += 0x7fffu + ((u >> 16) & 1u);       // round-to-nearest-even
  return (u16)(u >> 16);
}
__device__ __forceinline__ u32 pack2(float a, float b){
  return ((u32)f2bf(b) << 16) | (u32)f2bf(a);
}
// HW packed f32->bf16 (RNE, same bits as pack2), 1 instr instead of ~7.
__device__ __forceinline__ u32 cvtpk(float a, float b){
  u32 r;
  asm("v_cvt_pk_bf16_f32 %0, %1, %2" : "=v"(r) : "v"(a), "v"(b));
  return r;
}

// ---------- CSR build pass 1 (device body) ----------
// Two-pass re-read: pass A counts dst buckets; block reserves per-bucket
// absolute cursors; pass B re-reads edges and scatters at cursor.
__device__ __forceinline__ void binA_body(int blk, const int* __restrict__ ei,
                                          u32* __restrict__ gcnt,
                                          u32* __restrict__ buk,
                                          u32* hcnt){
  int t = threadIdx.x;
  for (int q = t; q < NBUK; q += 256) hcnt[q] = 0;
  __syncthreads();
  int e0 = blk * TILE_A;
  #pragma unroll 4
  for (int i = 0; i < TILE_A/256; i++){
    int e = e0 + i*256 + t;
    if (e < ETOT){
      int d = (e < EE) ? ei[EE + e] : (e - EE);
      atomicAdd(&hcnt[(u32)d / NPB], 1u);
    }
  }
  __syncthreads();
  for (int q = t; q < NBUK; q += 256){
    u32 c = hcnt[q];
    if (c) hcnt[q] = ((u32)q << 12) + atomicAdd(&gcnt[q], c);
  }
  __syncthreads();
  #pragma unroll 4
  for (int i = 0; i < TILE_A/256; i++){
    int e = e0 + i*256 + t;
    if (e < ETOT){
      int s, d;
      if (e < EE){ s = ei[e]; d = ei[EE + e]; } else { s = e - EE; d = s; }
      u32 b = (u32)d / NPB;
      u32 r = atomicAdd(&hcnt[b], 1u);
      buk[r] = ((u32)(d - (int)b*NPB) << 17) | (u32)s;
    }
  }
}

// ---------- MFMA GEMM (device body) ----------
// xp1[100k,32] = bf16(x) @ bf16(W1). Per kc-block: issue ALL 16 loads
// (8 x-float4 + 8 B-bfx8) before any pack/MFMA -> 16 outstanding loads/wave
// (was 2; latency-bound at VALUBusy 5%). cvt_pk does the f32->bf16x2 pack.
__device__ __forceinline__ void gemm_body(int gb,
    const float* __restrict__ x, const u16* __restrict__ WTb,
    const float* __restrict__ attS, const float* __restrict__ attD,
    u16* __restrict__ xp1, float* __restrict__ as1, float* __restrict__ ad1){
  int tid = threadIdx.x;
  int nb  = gb * 64;

  int lane = tid & 63, wid = tid >> 6;
  int m = lane & 15, quad = lane >> 4;
  int rowbase = wid * 16;
  int row = nb + rowbase + m; if (row >= NN) row = NN - 1;
  const float* xrow = x + (size_t)row * FIN + quad * 8;
  const u16* b0g = WTb + m * FIN + quad * 8;
  const u16* b1g = b0g + 16 * FIN;

  f32x4 acc0 = {0.f, 0.f, 0.f, 0.f};
  f32x4 acc1 = {0.f, 0.f, 0.f, 0.f};

  union Ubf { bfx8 v; u32 u[4]; };

  #pragma unroll
  for (int kc = 0; kc < 4; kc++){
    float4 fx[8];
    #pragma unroll
    for (int ks = 0; ks < 4; ks++){
      const float4* g = (const float4*)(xrow + kc*128 + ks*32);
      fx[2*ks]   = g[0];
      fx[2*ks+1] = g[1];
    }
    bfx8 b0v[4], b1v[4];
    #pragma unroll
    for (int ks = 0; ks < 4; ks++){
      b0v[ks] = *(const bfx8*)(b0g + kc*128 + ks*32);
      b1v[ks] = *(const bfx8*)(b1g + kc*128 + ks*32);
    }
    #pragma unroll
    for (int ks = 0; ks < 4; ks++){
      Ubf ua;
      ua.u[0] = cvtpk(fx[2*ks].x,   fx[2*ks].y);
      ua.u[1] = cvtpk(fx[2*ks].z,   fx[2*ks].w);
      ua.u[2] = cvtpk(fx[2*ks+1].x, fx[2*ks+1].y);
      ua.u[3] = cvtpk(fx[2*ks+1].z, fx[2*ks+1].w);
      acc0 = __builtin_amdgcn_mfma_f32_16x16x32_bf16(ua.v, b0v[ks], acc0, 0, 0, 0);
      acc1 = __builtin_amdgcn_mfma_f32_16x16x32_bf16(ua.v, b1v[ks], acc1, 0, 0, 0);
    }
  }

  #pragma unroll
  for (int t = 0; t < 2; t++){
    f32x4 acc = t ? acc1 : acc0;
    int colg = t*16 + m;
    float aS = attS[colg], aD = attD[colg];
    #pragma unroll
    for (int r = 0; r < 4; r++){
      int node = nb + rowbase + quad*4 + r;
      float v = acc[r];
      if (node < NN) xp1[(size_t)node*32 + colg] = f2bf(v);
      float ps = v * aS, pd = v * aD;
      ps += __shfl_xor(ps, 1); ps += __shfl_xor(ps, 2); ps += __shfl_xor(ps, 4);
      pd += __shfl_xor(pd, 1); pd += __shfl_xor(pd, 2); pd += __shfl_xor(pd, 4);
      if ((m & 7) == 0 && node < NN){
        as1[node*4 + (colg >> 3)] = ps;
        ad1[node*4 + (colg >> 3)] = pd;
      }
    }
  }
}

// ---------- CSR pass 2 (device body) ----------
// Inline scan of gcnt -> global base, per-dst count/scan, emit ranges + srcs.
__device__ __forceinline__ void scatterB_body(int b, const u32* __restrict__ gcnt,
                                              const u32* __restrict__ buk,
                                              int2* __restrict__ range,
                                              int* __restrict__ srcs){
  __shared__ u32 dcnt[NPB + 1];
  __shared__ u32 cur[NPB];
  __shared__ u32 red[256];
  int t = threadIdx.x;
  u32 acc = 0;
  for (int i = t; i < b; i += 256) acc += gcnt[i];
  red[t] = acc;
  if (t < NPB + 1) dcnt[t] = 0;
  __syncthreads();
  for (int o = 128; o > 0; o >>= 1){
    if (t < o) red[t] += red[t + o];
    __syncthreads();
  }
  u32 gb = red[0];                     // exclusive prefix: sum gcnt[0..b-1]
  u32 lo = (u32)b << 12;
  u32 hi = lo + gcnt[b];
  for (u32 j = lo + t; j < hi; j += 256)
    atomicAdd(&dcnt[(buk[j] >> 17) + 1], 1u);
  __syncthreads();
  for (int o = 1; o < 128; o <<= 1){
    u32 x = 0;
    if (t < NPB + 1 && t >= o) x = dcnt[t - o];
    __syncthreads();
    if (t < NPB + 1 && t >= o) dcnt[t] += x;
    __syncthreads();
  }
  if (t < NPB){
    u32 beg = gb + dcnt[t];
    cur[t] = beg;
    int node = b * NPB + t;
    if (node < NN){
      range[node] = make_int2((int)beg, (int)(gb + dcnt[t + 1]));
    }
  }
  __syncthreads();
  for (u32 j = lo + t; j < hi; j += 256){
    u32 p = buk[j];
    u32 pos = atomicAdd(&cur[p >> 17], 1u);
    srcs[pos] = (int)(p & 0x1FFFFu);
  }
}

// ---------- kernel wrappers ----------

// fat1: blocks [0, NBLK_A) = CSR pass 1; [NBLK_A, NBLK_A+G1) = gemm chunk 1.
__global__ void __launch_bounds__(256) k_fat1(const int* __restrict__ ei,
    u32* __restrict__ gcnt, u32* __restrict__ buk,
    const float* __restrict__ x, const u16* __restrict__ WTb,
    const float* __restrict__ attS, const float* __restrict__ attD,
    u16* __restrict__ xp1, float* __restrict__ as1, float* __restrict__ ad1){
  __shared__ u32 sm[NBUK];
  if (blockIdx.x < NBLK_A)
    binA_body(blockIdx.x, ei, gcnt, buk, sm);
  else
    gemm_body(blockIdx.x - NBLK_A, x, WTb, attS, attD, xp1, as1, ad1);
}

// fat2: blocks [0, NBUK) = CSR pass 2 (buk/gcnt complete: stream order after
// fat1); [NBUK, NBUK+G2) = gemm chunk 2.
__global__ void __launch_bounds__(256) k_fat2(
    const u32* __restrict__ gcnt, const u32* __restrict__ buk,
    int2* __restrict__ range, int* __restrict__ srcs,
    const float* __restrict__ x, const u16* __restrict__ WTb,
    const float* __restrict__ attS, const float* __restrict__ attD,
    u16* __restrict__ xp1, float* __restrict__ as1, float* __restrict__ ad1){
  if (blockIdx.x < NBUK)
    scatterB_body(blockIdx.x, gcnt, buk, range, srcs);
  else
    gemm_body(G1 + (int)blockIdx.x - NBUK, x, WTb, attS, attD, xp1, as1, ad1);
}

// fallback (serial) wrappers
__global__ void __launch_bounds__(256) k_binA(const int* __restrict__ ei,
                                              u32* __restrict__ gcnt,
                                              u32* __restrict__ buk){
  __shared__ u32 sm2[NBUK];
  binA_body(blockIdx.x, ei, gcnt, buk, sm2);
}

__global__ void __launch_bounds__(256) k_gemm1(
    const float* __restrict__ x, const u16* __restrict__ WTb,
    const float* __restrict__ attS, const float* __restrict__ attD,
    u16* __restrict__ xp1, float* __restrict__ as1, float* __restrict__ ad1){
  gemm_body(blockIdx.x, x, WTb, attS, attD, xp1, as1, ad1);
}

__global__ void __launch_bounds__(256) k_scatterB(const u32* __restrict__ gcnt,
                                                  const u32* __restrict__ buk,
                                                  int2* __restrict__ range,
                                                  int* __restrict__ srcs){
  scatterB_body(blockIdx.x, gcnt, buk, range, srcs);
}

// W1 transpose->bf16; also zeroes gcnt (replaces memset dispatch).
__global__ void k_prep_w(const float* __restrict__ W1, u16* __restrict__ WTb,
                         u32* __restrict__ gcnt){
  int i = blockIdx.x*blockDim.x + threadIdx.x;   // 0..16383
  if (i < NBUK) gcnt[i] = 0;
  if (i >= FIN*32) return;
  int k = i >> 5, c = i & 31;
  WTb[c*FIN + k] = f2bf(W1[i]);
}

// Layer-1 aggregation: one wave per dst. Lane = (edge slot e 0..3, chanpair l 0..15).
__global__ void __launch_bounds__(256) k_agg1(
    const int2* __restrict__ range, const int* __restrict__ srcs,
    const u32* __restrict__ xp1u, const float* __restrict__ as1,
    const float* __restrict__ ad1, const float* __restrict__ b1,
    u32* __restrict__ hfeatu){
  int wid = (blockIdx.x * 256 + threadIdx.x) >> 6;
  if (wid >= NN) return;
  int lane = threadIdx.x & 63;
  int e = lane >> 4;          // edge slot 0..3
  int l = lane & 15;          // channel pair: channels 2l, 2l+1
  int h = l >> 2;             // head
  int2 rr = range[wid];
  int beg = rr.x, end = rr.y;
  float ad = ad1[wid*4 + h];
  float num0 = 0.f, num1 = 0.f, den = 0.f;
  int j = beg + e;
  for (; j + 12 < end; j += 16){
    int s0 = srcs[j], s1 = srcs[j + 4], s2 = srcs[j + 8], s3 = srcs[j + 12];
    u32 v0 = xp1u[(size_t)s0*16 + l];
    u32 v1 = xp1u[(size_t)s1*16 + l];
    u32 v2 = xp1u[(size_t)s2*16 + l];
    u32 v3 = xp1u[(size_t)s3*16 + l];
    float z0 = as1[s0*4 + h] + ad;
    float z1 = as1[s1*4 + h] + ad;
    float z2 = as1[s2*4 + h] + ad;
    float z3 = as1[s3*4 + h] + ad;
    z0 = (z0 >= 0.f) ? z0 : 0.2f * z0;
    z1 = (z1 >= 0.f) ? z1 : 0.2f * z1;
    z2 = (z2 >= 0.f) ? z2 : 0.2f * z2;
    z3 = (z3 >= 0.f) ? z3 : 0.2f * z3;
    float w0 = __expf(z0), w1 = __expf(z1), w2 = __expf(z2), w3 = __expf(z3);
    num0 = fmaf(w0, lo16f(v0), num0); num1 = fmaf(w0, hi16f(v0), num1); den += w0;
    num0 = fmaf(w1, lo16f(v1), num0); num1 = fmaf(w1, hi16f(v1), num1); den += w1;
    num0 = fmaf(w2, lo16f(v2), num0); num1 = fmaf(w2, hi16f(v2), num1); den += w2;
    num0 = fmaf(w3, lo16f(v3), num0); num1 = fmaf(w3, hi16f(v3), num1); den += w3;
  }
  if (j + 4 < end){
    int s0 = srcs[j], s1 = srcs[j + 4];
    u32 v0 = xp1u[(size_t)s0*16 + l];
    u32 v1 = xp1u[(size_t)s1*16 + l];
    float z0 = as1[s0*4 + h] + ad;
    float z1 = as1[s1*4 + h] + ad;
    z0 = (z0 >= 0.f) ? z0 : 0.2f * z0;
    z1 = (z1 >= 0.f) ? z1 : 0.2f * z1;
    float w0 = __expf(z0), w1 = __expf(z1);
    num0 = fmaf(w0, lo16f(v0), num0); num1 = fmaf(w0, hi16f(v0), num1); den += w0;
    num0 = fmaf(w1, lo16f(v1), num0); num1 = fmaf(w1, hi16f(v1), num1); den += w1;
    j += 8;
  }
  for (; j < end; j += 4){
    int s0 = srcs[j];
    u32 v0 = xp1u[(size_t)s0*16 + l];
    float z0 = as1[s0*4 + h] + ad;
    z0 = (z0 >= 0.f) ? z0 : 0.2f * z0;
    float w0 = __expf(z0);
    num0 = fmaf(w0, lo16f(v0), num0); num1 = fmaf(w0, hi16f(v0), num1); den += w0;
  }
  num0 += __shfl_xor(num0, 16); num0 += __shfl_xor(num0, 32);
  num1 += __shfl_xor(num1, 16); num1 += __shfl_xor(num1, 32);
  den  += __shfl_xor(den, 16);  den  += __shfl_xor(den, 32);
  if (e == 0){
    float o0 = num0 / den + b1[2*l];
    float o1 = num1 / den + b1[2*l + 1];
    o0 = (o0 > 0.f) ? o0 : (__expf(o0) - 1.f);   // ELU
    o1 = (o1 > 0.f) ? o1 : (__expf(o1) - 1.f);
    hfeatu[(size_t)wid*16 + l] = pack2(o0, o1);
  }
}

// h[100k,32] @ W2[32,8] + attention scalars for layer 2.
__global__ void k_feat2(const u16* __restrict__ hfeat, const float* __restrict__ W2,
                        const float* __restrict__ attS, const float* __restrict__ attD,
                        float* __restrict__ xp2, float* __restrict__ as2,
                        float* __restrict__ ad2){
  int n = blockIdx.x*blockDim.x + threadIdx.x;
  if (n >= NN) return;
  const u16* hr = hfeat + (size_t)n*32;
  float h[32];
  #pragma unroll
  for (int k = 0; k < 32; k++) h[k] = bf2f(hr[k]);
  float o[8];
  #pragma unroll
  for (int j = 0; j < 8; j++) o[j] = 0.f;
  #pragma unroll
  for (int k = 0; k < 32; k++){
    #pragma unroll
    for (int j = 0; j < 8; j++) o[j] = fmaf(h[k], W2[k*8 + j], o[j]);
  }
  float s = 0.f, d = 0.f;
  #pragma unroll
  for (int j = 0; j < 8; j++){
    xp2[(size_t)n*8 + j] = o[j];
    s = fmaf(o[j], attS[j], s);
    d = fmaf(o[j], attD[j], d);
  }
  as2[n] = s; ad2[n] = d;
}

// Layer-2 aggregation: one wave per dst, 32 edges in flight per iteration.
__global__ void __launch_bounds__(256) k_agg2(
    const int2* __restrict__ range, const int* __restrict__ srcs,
    const float* __restrict__ xp2, const float* __restrict__ as2,
    const float* __restrict__ ad2, const float* __restrict__ b2,
    float* __restrict__ out){
  int wid = (blockIdx.x * 256 + threadIdx.x) >> 6;
  if (wid >= NN) return;
  int lane = threadIdx.x & 63;
  int p = lane >> 3, c = lane & 7;
  int2 rr = range[wid];
  int beg = rr.x, end = rr.y;
  float ad = ad2[wid];
  float num = 0.f, den = 0.f;
  int j = beg + p;
  for (; j + 24 < end; j += 32){
    int s0 = srcs[j], s1 = srcs[j + 8], s2 = srcs[j + 16], s3 = srcs[j + 24];
    float v0 = xp2[(size_t)s0*8 + c];
    float v1 = xp2[(size_t)s1*8 + c];
    float v2 = xp2[(size_t)s2*8 + c];
    float v3 = xp2[(size_t)s3*8 + c];
    float z0 = as2[s0] + ad;
    float z1 = as2[s1] + ad;
    float z2 = as2[s2] + ad;
    float z3 = as2[s3] + ad;
    z0 = (z0 >= 0.f) ? z0 : 0.2f * z0;
    z1 = (z1 >= 0.f) ? z1 : 0.2f * z1;
    z2 = (z2 >= 0.f) ? z2 : 0.2f * z2;
    z3 = (z3 >= 0.f) ? z3 : 0.2f * z3;
    float w0 = __expf(z0), w1 = __expf(z1), w2 = __expf(z2), w3 = __expf(z3);
    num = fmaf(w0, v0, num); den += w0;
    num = fmaf(w1, v1, num); den += w1;
    num = fmaf(w2, v2, num); den += w2;
    num = fmaf(w3, v3, num); den += w3;
  }
  if (j + 8 < end){
    int s0 = srcs[j], s1 = srcs[j + 8];
    float v0 = xp2[(size_t)s0*8 + c];
    float v1 = xp2[(size_t)s1*8 + c];
    float z0 = as2[s0] + ad;
    float z1 = as2[s1] + ad;
    z0 = (z0 >= 0.f) ? z0 : 0.2f * z0;
    z1 = (z1 >= 0.f) ? z1 : 0.2f * z1;
    float w0 = __expf(z0), w1 = __expf(z1);
    num = fmaf(w0, v0, num); den += w0;
    num = fmaf(w1, v1, num); den += w1;
    j += 16;
  }
  for (; j < end; j += 8){
    int s0 = srcs[j];
    float v0 = xp2[(size_t)s0*8 + c];
    float z0 = as2[s0] + ad;
    z0 = (z0 >= 0.f) ? z0 : 0.2f * z0;
    float w0 = __expf(z0);
    num = fmaf(w0, v0, num); den += w0;
  }
  num += __shfl_xor(num, 8);  den += __shfl_xor(den, 8);
  num += __shfl_xor(num, 16); den += __shfl_xor(den, 16);
  num += __shfl_xor(num, 32); den += __shfl_xor(den, 32);
  if (p == 0){
    out[(size_t)wid*8 + c] = num / den + b2[c];
  }
}

extern "C" void kernel_launch(void* const* d_in, const int* in_sizes, int n_in,
                              void* d_out, int out_size, void* d_ws, size_t ws_size,
                              hipStream_t stream){
  (void)in_sizes; (void)n_in; (void)out_size;
  const float* x   = (const float*)d_in[0];
  const int*   ei  = (const int*)d_in[1];
  const float* W1  = (const float*)d_in[2];
  const float* aS1 = (const float*)d_in[3];
  const float* aD1 = (const float*)d_in[4];
  const float* b1  = (const float*)d_in[5];
  const float* W2  = (const float*)d_in[6];
  const float* aS2 = (const float*)d_in[7];
  const float* aD2 = (const float*)d_in[8];
  const float* b2  = (const float*)d_in[9];
  float* out = (float*)d_out;

  char* w = (char*)d_ws;
  auto alloc = [&](size_t bytes) -> char* {
    char* p = w; w += (bytes + 15) & ~(size_t)15; return p;
  };

  int2*  range  = (int2*)alloc((size_t)NN*8);       // 800 KB
  int*   srcs   = (int*)alloc((size_t)ETOT*4);      // 13.2 MB
  u16*   xp1    = (u16*)alloc((size_t)NN*64);       // 6.4 MB
  float* as1    = (float*)alloc((size_t)NN*16);     // 1.6 MB
  float* ad1    = (float*)alloc((size_t)NN*16);     // 1.6 MB
  u16*   hfeat  = (u16*)alloc((size_t)NN*64);       // 6.4 MB
  float* xp2    = (float*)alloc((size_t)NN*32);     // 3.2 MB
  float* as2    = (float*)alloc((size_t)NN*4);
  float* ad2    = (float*)alloc((size_t)NN*4);
  u16*   WTb    = (u16*)alloc(32*512*2);
  u32*   gcnt   = (u32*)alloc(NBUK*4);
  size_t base_need = (size_t)(w - (char*)d_ws);
  size_t buk_bytes = (size_t)NBUK * CAP * 4;        // 16.8 MB
  bool overlap = (ws_size >= base_need + buk_bytes);

  u32* buk;
  if (overlap){
    buk = (u32*)alloc(buk_bytes);                   // dedicated slab: safe to co-run
  } else {
    // aliased slab: buk spans xp1..xp2 (19.2 MB >= 16.8 MB); dead before gemm
    // writes xp1 because the fallback serializes binA -> scatterB -> gemm1.
    buk = (u32*)xp1;
  }

  k_prep_w  <<<64, 256, 0, stream>>>(W1, WTb, gcnt);
  if (overlap){
    k_fat1  <<<NBLK_A + G1, 256, 0, stream>>>(ei, gcnt, buk, x, WTb, aS1, aD1,
                                              xp1, as1, ad1);
    k_fat2  <<<NBUK + G2, 256, 0, stream>>>(gcnt, buk, range, srcs, x, WTb,
                                            aS1, aD1, xp1, as1, ad1);
  } else {
    k_binA  <<<NBLK_A, 256, 0, stream>>>(ei, gcnt, buk);
    k_scatterB<<<NBUK, 256, 0, stream>>>(gcnt, buk, range, srcs);
    k_gemm1 <<<NBLK_G, 256, 0, stream>>>(x, WTb, aS1, aD1, xp1, as1, ad1);
  }
  k_agg1    <<<NN/4, 256, 0, stream>>>(range, srcs, (const u32*)xp1, as1, ad1, b1, (u32*)hfeat);
  k_feat2   <<<(NN+255)/256, 256, 0, stream>>>(hfeat, W2, aS2, aD2, xp2, as2, ad2);
  k_agg2    <<<NN/4, 256, 0, stream>>>(range, srcs, xp2, as2, ad2, b2, out);
}

// Round 8
// 467.986 us; speedup vs baseline: 1.1200x; 1.1200x over previous
//
#include <hip/hip_runtime.h>

typedef unsigned short u16;
typedef unsigned int   u32;

#define NN  100000
#define EE  3200000
#define ETOT 3300000   // EE + NN self-loops
#define FIN 512
#define NBUK 512
#define NPB  196       // nodes per bucket; 512*196 = 100352 >= NN
#define CAP  8192      // bucket capacity in buk (max real bucket ~6900)
#define TILE_A 8192    // edges per binA block (32/thread in registers)
#define NBLK_A ((ETOT + TILE_A - 1) / TILE_A)   // 403
#define NBLK_G ((NN + 63) / 64)                 // 1563 gemm blocks

typedef __attribute__((ext_vector_type(8))) short bfx8;   // 8 bf16 (4 VGPRs)
typedef __attribute__((ext_vector_type(4))) float f32x4;  // MFMA C/D

__device__ __forceinline__ float bf2f(u16 u){ return __uint_as_float(((u32)u) << 16); }
__device__ __forceinline__ float lo16f(u32 v){ return __uint_as_float(v << 16); }
__device__ __forceinline__ float hi16f(u32 v){ return __uint_as_float(v & 0xffff0000u); }
__device__ __forceinline__ u16 f2bf(float f){
  u32 u = __float_as_uint(f);
  u += 0x7fffu + ((u >> 16) & 1u);       // round-to-nearest-even
  return (u16)(u >> 16);
}
__device__ __forceinline__ u32 pack2(float a, float b){
  return ((u32)f2bf(b) << 16) | (u32)f2bf(a);
}
// HW packed f32->bf16 (RNE, same bits as pack2), 1 instr instead of ~7.
// Verified end-to-end round 7 (absmax unchanged).
__device__ __forceinline__ u32 cvtpk(float a, float b){
  u32 r;
  asm("v_cvt_pk_bf16_f32 %0, %1, %2" : "=v"(r) : "v"(a), "v"(b));
  return r;
}

// ---------- CSR build pass 1 (device body) ----------
// Round-3 proven form (fat measured 121 us): single edge read, pk/meta in
// registers (32/thread), per-block bucket-chunk reservation -> line-friendly
// buk writes. Do NOT cap VGPR (round 4: launch_bounds(256,8) -> 80 MB spill).
__device__ __forceinline__ void binA_body(int blk, const int* __restrict__ ei,
                                          u32* __restrict__ gcnt,
                                          u32* __restrict__ buk,
                                          u32* hcnt, u32* hbase){
  int t = threadIdx.x;
  hcnt[t] = 0; hcnt[t + 256] = 0;
  __syncthreads();
  int e0 = blk * TILE_A;
  u32 pk[32], meta[32];
  #pragma unroll
  for (int i = 0; i < 32; i++){
    int e = e0 + i*256 + t;
    if (e < ETOT){
      int s, d;
      if (e < EE){ s = ei[e]; d = ei[EE + e]; } else { s = e - EE; d = s; }
      u32 b = (u32)d / NPB;
      pk[i] = ((u32)(d - (int)b*NPB) << 17) | (u32)s;
      u32 r = atomicAdd(&hcnt[b], 1u);
      meta[i] = (b << 13) | r;          // r < 8192
    } else meta[i] = 0xFFFFFFFFu;
  }
  __syncthreads();
  for (int q = t; q < NBUK; q += 256){
    u32 c = hcnt[q];
    if (c) hbase[q] = atomicAdd(&gcnt[q], c);
  }
  __syncthreads();
  #pragma unroll
  for (int i = 0; i < 32; i++){
    if (meta[i] != 0xFFFFFFFFu){
      u32 b = meta[i] >> 13, r = meta[i] & 8191u;
      buk[((u32)b << 13) + hbase[b] + r] = pk[i];
    }
  }
}

// ---------- MFMA GEMM (device body) ----------
// Round-3 proven form: W LDS-staged (one barrier), A from global coalesced.
// + round-7 micro-wins: batch the 8 x-float4 loads per kc (MLP), cvt_pk pack.
__device__ __forceinline__ void gemm_body(int gb,
    const float* __restrict__ x, const u16* __restrict__ WTb,
    const float* __restrict__ attS, const float* __restrict__ attD,
    u16* __restrict__ xp1, float* __restrict__ as1, float* __restrict__ ad1,
    u16* ws){
  int tid = threadIdx.x;
  int nb  = gb * 64;

  {
    int r = tid >> 3, seg = tid & 7;
    const uint4* src = (const uint4*)(WTb + r*FIN + seg*64);
    uint4* dst = (uint4*)(ws + r*520 + seg*64);
    #pragma unroll
    for (int i = 0; i < 8; i++) dst[i] = src[i];
  }
  __syncthreads();

  int lane = tid & 63, wid = tid >> 6;
  int m = lane & 15, quad = lane >> 4;
  int rowbase = wid * 16;
  int row = nb + rowbase + m; if (row >= NN) row = NN - 1;
  const float* xrow = x + (size_t)row * FIN + quad * 8;
  const u16* b0_base = ws + m * 520 + quad * 8;
  const u16* b1_base = b0_base + 16 * 520;

  f32x4 acc0 = {0.f, 0.f, 0.f, 0.f};
  f32x4 acc1 = {0.f, 0.f, 0.f, 0.f};

  union Ubf { bfx8 v; u32 u[4]; };

  #pragma unroll
  for (int kc = 0; kc < 4; kc++){
    float4 fx[8];
    #pragma unroll
    for (int ks = 0; ks < 4; ks++){
      const float4* g = (const float4*)(xrow + kc*128 + ks*32);
      fx[2*ks]   = g[0];
      fx[2*ks+1] = g[1];
    }
    #pragma unroll
    for (int ks = 0; ks < 4; ks++){
      Ubf ua;
      ua.u[0] = cvtpk(fx[2*ks].x,   fx[2*ks].y);
      ua.u[1] = cvtpk(fx[2*ks].z,   fx[2*ks].w);
      ua.u[2] = cvtpk(fx[2*ks+1].x, fx[2*ks+1].y);
      ua.u[3] = cvtpk(fx[2*ks+1].z, fx[2*ks+1].w);
      bfx8 b0 = *(const bfx8*)(b0_base + kc*128 + ks*32);
      bfx8 b1 = *(const bfx8*)(b1_base + kc*128 + ks*32);
      acc0 = __builtin_amdgcn_mfma_f32_16x16x32_bf16(ua.v, b0, acc0, 0, 0, 0);
      acc1 = __builtin_amdgcn_mfma_f32_16x16x32_bf16(ua.v, b1, acc1, 0, 0, 0);
    }
  }

  #pragma unroll
  for (int t = 0; t < 2; t++){
    f32x4 acc = t ? acc1 : acc0;
    int colg = t*16 + m;
    float aS = attS[colg], aD = attD[colg];
    #pragma unroll
    for (int r = 0; r < 4; r++){
      int node = nb + rowbase + quad*4 + r;
      float v = acc[r];
      if (node < NN) xp1[(size_t)node*32 + colg] = f2bf(v);
      float ps = v * aS, pd = v * aD;
      ps += __shfl_xor(ps, 1); ps += __shfl_xor(ps, 2); ps += __shfl_xor(ps, 4);
      pd += __shfl_xor(pd, 1); pd += __shfl_xor(pd, 2); pd += __shfl_xor(pd, 4);
      if ((m & 7) == 0 && node < NN){
        as1[node*4 + (colg >> 3)] = ps;
        ad1[node*4 + (colg >> 3)] = pd;
      }
    }
  }
}

// ---------- kernel wrappers ----------

// Fat kernel (round-3 proven): blocks [0, NBLK_A) = CSR pass 1, rest = GEMM.
// Disjoint memory (requires un-aliased buk). 33 KB LDS union -> 4 blocks/CU.
__global__ void __launch_bounds__(256) k_fat(const int* __restrict__ ei,
    u32* __restrict__ gcnt, u32* __restrict__ buk,
    const float* __restrict__ x, const u16* __restrict__ WTb,
    const float* __restrict__ attS, const float* __restrict__ attD,
    u16* __restrict__ xp1, float* __restrict__ as1, float* __restrict__ ad1){
  __shared__ __align__(16) char sm[32 * 520 * 2];   // union: binA tables | gemm ws
  if (blockIdx.x < NBLK_A)
    binA_body(blockIdx.x, ei, gcnt, buk, (u32*)sm, (u32*)sm + NBUK);
  else
    gemm_body(blockIdx.x - NBLK_A, x, WTb, attS, attD, xp1, as1, ad1, (u16*)sm);
}

__global__ void __launch_bounds__(256) k_binA(const int* __restrict__ ei,
                                              u32* __restrict__ gcnt,
                                              u32* __restrict__ buk){
  __shared__ u32 sm2[NBUK*2];
  binA_body(blockIdx.x, ei, gcnt, buk, sm2, sm2 + NBUK);
}

__global__ void __launch_bounds__(256) k_gemm1(
    const float* __restrict__ x, const u16* __restrict__ WTb,
    const float* __restrict__ attS, const float* __restrict__ attD,
    u16* __restrict__ xp1, float* __restrict__ as1, float* __restrict__ ad1){
  __shared__ u16 ws[32 * 520];
  gemm_body(blockIdx.x, x, WTb, attS, attD, xp1, as1, ad1, ws);
}

// CSR pass 2: inline scan of gcnt -> global base, per-dst count/scan/scatter.
__global__ void __launch_bounds__(256) k_scatterB(const u32* __restrict__ gcnt,
                                                  const u32* __restrict__ buk,
                                                  int2* __restrict__ range,
                                                  int* __restrict__ srcs){
  __shared__ u32 dcnt[NPB + 1];
  __shared__ u32 cur[NPB];
  __shared__ u32 red[256];
  int b = blockIdx.x, t = threadIdx.x;
  u32 acc = 0;
  for (int i = t; i < b; i += 256) acc += gcnt[i];
  red[t] = acc;
  if (t < NPB + 1) dcnt[t] = 0;
  __syncthreads();
  for (int o = 128; o > 0; o >>= 1){
    if (t < o) red[t] += red[t + o];
    __syncthreads();
  }
  u32 gb = red[0];                     // exclusive prefix: sum gcnt[0..b-1]
  u32 lo = (u32)b << 13;
  u32 hi = lo + gcnt[b];
  for (u32 j = lo + t; j < hi; j += 256)
    atomicAdd(&dcnt[(buk[j] >> 17) + 1], 1u);
  __syncthreads();
  for (int o = 1; o < 256; o <<= 1){
    u32 x = 0;
    if (t < NPB + 1 && t >= o) x = dcnt[t - o];
    __syncthreads();
    if (t < NPB + 1 && t >= o) dcnt[t] += x;
    __syncthreads();
  }
  if (t < NPB){
    u32 beg = gb + dcnt[t];
    cur[t] = beg;
    int node = b * NPB + t;
    if (node < NN){
      range[node] = make_int2((int)beg, (int)(gb + dcnt[t + 1]));
    }
  }
  __syncthreads();
  for (u32 j = lo + t; j < hi; j += 256){
    u32 p = buk[j];
    u32 pos = atomicAdd(&cur[p >> 17], 1u);
    srcs[pos] = (int)(p & 0x1FFFFu);
  }
}

// W1 transpose->bf16; also zeroes gcnt (replaces memset dispatch).
__global__ void k_prep_w(const float* __restrict__ W1, u16* __restrict__ WTb,
                         u32* __restrict__ gcnt){
  int i = blockIdx.x*blockDim.x + threadIdx.x;   // 0..16383
  if (i < NBUK) gcnt[i] = 0;
  if (i >= FIN*32) return;
  int k = i >> 5, c = i & 31;
  WTb[c*FIN + k] = f2bf(W1[i]);
}

// Layer-1 aggregation: one wave per dst. Lane = (edge slot e 0..3, chanpair l 0..15).
// 4x unroll: 16 edges (16 row-gathers) in flight per iteration.
__global__ void __launch_bounds__(256) k_agg1(
    const int2* __restrict__ range, const int* __restrict__ srcs,
    const u32* __restrict__ xp1u, const float* __restrict__ as1,
    const float* __restrict__ ad1, const float* __restrict__ b1,
    u32* __restrict__ hfeatu){
  int wid = (blockIdx.x * 256 + threadIdx.x) >> 6;
  if (wid >= NN) return;
  int lane = threadIdx.x & 63;
  int e = lane >> 4;          // edge slot 0..3
  int l = lane & 15;          // channel pair: channels 2l, 2l+1
  int h = l >> 2;             // head
  int2 rr = range[wid];
  int beg = rr.x, end = rr.y;
  float ad = ad1[wid*4 + h];
  float num0 = 0.f, num1 = 0.f, den = 0.f;
  int j = beg + e;
  for (; j + 12 < end; j += 16){
    int s0 = srcs[j], s1 = srcs[j + 4], s2 = srcs[j + 8], s3 = srcs[j + 12];
    u32 v0 = xp1u[(size_t)s0*16 + l];
    u32 v1 = xp1u[(size_t)s1*16 + l];
    u32 v2 = xp1u[(size_t)s2*16 + l];
    u32 v3 = xp1u[(size_t)s3*16 + l];
    float z0 = as1[s0*4 + h] + ad;
    float z1 = as1[s1*4 + h] + ad;
    float z2 = as1[s2*4 + h] + ad;
    float z3 = as1[s3*4 + h] + ad;
    z0 = (z0 >= 0.f) ? z0 : 0.2f * z0;
    z1 = (z1 >= 0.f) ? z1 : 0.2f * z1;
    z2 = (z2 >= 0.f) ? z2 : 0.2f * z2;
    z3 = (z3 >= 0.f) ? z3 : 0.2f * z3;
    float w0 = __expf(z0), w1 = __expf(z1), w2 = __expf(z2), w3 = __expf(z3);
    num0 = fmaf(w0, lo16f(v0), num0); num1 = fmaf(w0, hi16f(v0), num1); den += w0;
    num0 = fmaf(w1, lo16f(v1), num0); num1 = fmaf(w1, hi16f(v1), num1); den += w1;
    num0 = fmaf(w2, lo16f(v2), num0); num1 = fmaf(w2, hi16f(v2), num1); den += w2;
    num0 = fmaf(w3, lo16f(v3), num0); num1 = fmaf(w3, hi16f(v3), num1); den += w3;
  }
  if (j + 4 < end){
    int s0 = srcs[j], s1 = srcs[j + 4];
    u32 v0 = xp1u[(size_t)s0*16 + l];
    u32 v1 = xp1u[(size_t)s1*16 + l];
    float z0 = as1[s0*4 + h] + ad;
    float z1 = as1[s1*4 + h] + ad;
    z0 = (z0 >= 0.f) ? z0 : 0.2f * z0;
    z1 = (z1 >= 0.f) ? z1 : 0.2f * z1;
    float w0 = __expf(z0), w1 = __expf(z1);
    num0 = fmaf(w0, lo16f(v0), num0); num1 = fmaf(w0, hi16f(v0), num1); den += w0;
    num0 = fmaf(w1, lo16f(v1), num0); num1 = fmaf(w1, hi16f(v1), num1); den += w1;
    j += 8;
  }
  for (; j < end; j += 4){
    int s0 = srcs[j];
    u32 v0 = xp1u[(size_t)s0*16 + l];
    float z0 = as1[s0*4 + h] + ad;
    z0 = (z0 >= 0.f) ? z0 : 0.2f * z0;
    float w0 = __expf(z0);
    num0 = fmaf(w0, lo16f(v0), num0); num1 = fmaf(w0, hi16f(v0), num1); den += w0;
  }
  num0 += __shfl_xor(num0, 16); num0 += __shfl_xor(num0, 32);
  num1 += __shfl_xor(num1, 16); num1 += __shfl_xor(num1, 32);
  den  += __shfl_xor(den, 16);  den  += __shfl_xor(den, 32);
  if (e == 0){
    float o0 = num0 / den + b1[2*l];
    float o1 = num1 / den + b1[2*l + 1];
    o0 = (o0 > 0.f) ? o0 : (__expf(o0) - 1.f);   // ELU
    o1 = (o1 > 0.f) ? o1 : (__expf(o1) - 1.f);
    hfeatu[(size_t)wid*16 + l] = pack2(o0, o1);
  }
}

// h[100k,32] @ W2[32,8] + attention scalars for layer 2.
__global__ void k_feat2(const u16* __restrict__ hfeat, const float* __restrict__ W2,
                        const float* __restrict__ attS, const float* __restrict__ attD,
                        float* __restrict__ xp2, float* __restrict__ as2,
                        float* __restrict__ ad2){
  int n = blockIdx.x*blockDim.x + threadIdx.x;
  if (n >= NN) return;
  const u16* hr = hfeat + (size_t)n*32;
  float h[32];
  #pragma unroll
  for (int k = 0; k < 32; k++) h[k] = bf2f(hr[k]);
  float o[8];
  #pragma unroll
  for (int j = 0; j < 8; j++) o[j] = 0.f;
  #pragma unroll
  for (int k = 0; k < 32; k++){
    #pragma unroll
    for (int j = 0; j < 8; j++) o[j] = fmaf(h[k], W2[k*8 + j], o[j]);
  }
  float s = 0.f, d = 0.f;
  #pragma unroll
  for (int j = 0; j < 8; j++){
    xp2[(size_t)n*8 + j] = o[j];
    s = fmaf(o[j], attS[j], s);
    d = fmaf(o[j], attD[j], d);
  }
  as2[n] = s; ad2[n] = d;
}

// Layer-2 aggregation: one wave per dst, 32 edges in flight per iteration.
__global__ void __launch_bounds__(256) k_agg2(
    const int2* __restrict__ range, const int* __restrict__ srcs,
    const float* __restrict__ xp2, const float* __restrict__ as2,
    const float* __restrict__ ad2, const float* __restrict__ b2,
    float* __restrict__ out){
  int wid = (blockIdx.x * 256 + threadIdx.x) >> 6;
  if (wid >= NN) return;
  int lane = threadIdx.x & 63;
  int p = lane >> 3, c = lane & 7;
  int2 rr = range[wid];
  int beg = rr.x, end = rr.y;
  float ad = ad2[wid];
  float num = 0.f, den = 0.f;
  int j = beg + p;
  for (; j + 24 < end; j += 32){
    int s0 = srcs[j], s1 = srcs[j + 8], s2 = srcs[j + 16], s3 = srcs[j + 24];
    float v0 = xp2[(size_t)s0*8 + c];
    float v1 = xp2[(size_t)s1*8 + c];
    float v2 = xp2[(size_t)s2*8 + c];
    float v3 = xp2[(size_t)s3*8 + c];
    float z0 = as2[s0] + ad;
    float z1 = as2[s1] + ad;
    float z2 = as2[s2] + ad;
    float z3 = as2[s3] + ad;
    z0 = (z0 >= 0.f) ? z0 : 0.2f * z0;
    z1 = (z1 >= 0.f) ? z1 : 0.2f * z1;
    z2 = (z2 >= 0.f) ? z2 : 0.2f * z2;
    z3 = (z3 >= 0.f) ? z3 : 0.2f * z3;
    float w0 = __expf(z0), w1 = __expf(z1), w2 = __expf(z2), w3 = __expf(z3);
    num = fmaf(w0, v0, num); den += w0;
    num = fmaf(w1, v1, num); den += w1;
    num = fmaf(w2, v2, num); den += w2;
    num = fmaf(w3, v3, num); den += w3;
  }
  if (j + 8 < end){
    int s0 = srcs[j], s1 = srcs[j + 8];
    float v0 = xp2[(size_t)s0*8 + c];
    float v1 = xp2[(size_t)s1*8 + c];
    float z0 = as2[s0] + ad;
    float z1 = as2[s1] + ad;
    z0 = (z0 >= 0.f) ? z0 : 0.2f * z0;
    z1 = (z1 >= 0.f) ? z1 : 0.2f * z1;
    float w0 = __expf(z0), w1 = __expf(z1);
    num = fmaf(w0, v0, num); den += w0;
    num = fmaf(w1, v1, num); den += w1;
    j += 16;
  }
  for (; j < end; j += 8){
    int s0 = srcs[j];
    float v0 = xp2[(size_t)s0*8 + c];
    float z0 = as2[s0] + ad;
    z0 = (z0 >= 0.f) ? z0 : 0.2f * z0;
    float w0 = __expf(z0);
    num = fmaf(w0, v0, num); den += w0;
  }
  num += __shfl_xor(num, 8);  den += __shfl_xor(den, 8);
  num += __shfl_xor(num, 16); den += __shfl_xor(den, 16);
  num += __shfl_xor(num, 32); den += __shfl_xor(den, 32);
  if (p == 0){
    out[(size_t)wid*8 + c] = num / den + b2[c];
  }
}

extern "C" void kernel_launch(void* const* d_in, const int* in_sizes, int n_in,
                              void* d_out, int out_size, void* d_ws, size_t ws_size,
                              hipStream_t stream){
  (void)in_sizes; (void)n_in; (void)out_size;
  const float* x   = (const float*)d_in[0];
  const int*   ei  = (const int*)d_in[1];
  const float* W1  = (const float*)d_in[2];
  const float* aS1 = (const float*)d_in[3];
  const float* aD1 = (const float*)d_in[4];
  const float* b1  = (const float*)d_in[5];
  const float* W2  = (const float*)d_in[6];
  const float* aS2 = (const float*)d_in[7];
  const float* aD2 = (const float*)d_in[8];
  const float* b2  = (const float*)d_in[9];
  float* out = (float*)d_out;

  char* w = (char*)d_ws;
  auto alloc = [&](size_t bytes) -> char* {
    char* p = w; w += (bytes + 15) & ~(size_t)15; return p;
  };

  int2*  range  = (int2*)alloc((size_t)NN*8);       // 800 KB
  int*   srcs   = (int*)alloc((size_t)ETOT*4);      // 13.2 MB
  u16*   xp1    = (u16*)alloc((size_t)NN*64);       // 6.4 MB
  float* as1    = (float*)alloc((size_t)NN*16);     // 1.6 MB
  float* ad1    = (float*)alloc((size_t)NN*16);     // 1.6 MB
  u16*   hfeat  = (u16*)alloc((size_t)NN*64);       // 6.4 MB
  float* xp2    = (float*)alloc((size_t)NN*32);     // 3.2 MB
  float* as2    = (float*)alloc((size_t)NN*4);
  float* ad2    = (float*)alloc((size_t)NN*4);
  u16*   WTb    = (u16*)alloc(32*512*2);
  u32*   gcnt   = (u32*)alloc(NBUK*4);
  size_t base_need = (size_t)(w - (char*)d_ws);
  size_t buk_bytes = (size_t)NBUK * CAP * 4;        // 16.8 MB
  bool overlap = (ws_size >= base_need + buk_bytes);

  u32* buk;
  if (overlap){
    buk = (u32*)alloc(buk_bytes);                   // dedicated slab: binA || gemm safe
  } else {
    // aliased slab: buk spans xp1..xp2 (19.2 MB >= 16.8 MB); dead before gemm
    // writes xp1 because the fallback serializes binA -> scatterB -> gemm1.
    buk = (u32*)xp1;
  }

  k_prep_w  <<<64, 256, 0, stream>>>(W1, WTb, gcnt);
  if (overlap){
    k_fat   <<<NBLK_A + NBLK_G, 256, 0, stream>>>(ei, gcnt, buk, x, WTb, aS1, aD1,
                                                  xp1, as1, ad1);
    k_scatterB<<<NBUK, 256, 0, stream>>>(gcnt, buk, range, srcs);
  } else {
    k_binA  <<<NBLK_A, 256, 0, stream>>>(ei, gcnt, buk);
    k_scatterB<<<NBUK, 256, 0, stream>>>(gcnt, buk, range, srcs);
    k_gemm1 <<<NBLK_G, 256, 0, stream>>>(x, WTb, aS1, aD1, xp1, as1, ad1);
  }
  k_agg1    <<<NN/4, 256, 0, stream>>>(range, srcs, (const u32*)xp1, as1, ad1, b1, (u32*)hfeat);
  k_feat2   <<<(NN+255)/256, 256, 0, stream>>>(hfeat, W2, aS2, aD2, xp2, as2, ad2);
  k_agg2    <<<NN/4, 256, 0, stream>>>(range, srcs, xp2, as2, ad2, b2, out);
}